// Round 1
// baseline (284.976 us; speedup 1.0000x reference)
//
#include <hip/hip_runtime.h>
#include <stdint.h>

typedef __attribute__((ext_vector_type(8))) __bf16 bf16x8;
typedef __attribute__((ext_vector_type(4))) __bf16 bf16x4;
typedef __attribute__((ext_vector_type(4))) float f32x4;

#define MFMA16(a, b, c) __builtin_amdgcn_mfma_f32_16x16x32_bf16(a, b, c, 0, 0, 0)

// ---------------------------------------------------------------- casts
__global__ __launch_bounds__(256) void k_cast_bf16(const float* __restrict__ in,
                                                   __bf16* __restrict__ out, int n) {
    int i = (blockIdx.x * 256 + threadIdx.x) * 4;
    if (i >= n) return;
    float4 v = *(const float4*)(in + i);
    bf16x4 o;
    o.x = (__bf16)v.x; o.y = (__bf16)v.y; o.z = (__bf16)v.z; o.w = (__bf16)v.w;
    *(bf16x4*)(out + i) = o;
}

// in [R][C] fp32 -> out [C][R] bf16   (R, C multiples of 32)
__global__ __launch_bounds__(256) void k_transpose_cast(const float* __restrict__ in,
                                                        __bf16* __restrict__ out,
                                                        int R, int C) {
    __shared__ __bf16 tile[32][33];
    int c0 = blockIdx.x * 32, r0 = blockIdx.y * 32;
    int tx = threadIdx.x, ty = threadIdx.y;  // block (32, 8)
#pragma unroll
    for (int i = 0; i < 4; i++)
        tile[ty + i * 8][tx] = (__bf16)in[(size_t)(r0 + ty + i * 8) * C + c0 + tx];
    __syncthreads();
#pragma unroll
    for (int i = 0; i < 4; i++)
        out[(size_t)(c0 + ty + i * 8) * R + r0 + tx] = tile[tx][ty + i * 8];
}

// ---------------------------------------------------------------- QKV GEMM
// C[4096,3072] = A[4096,1024] @ Bt[3072,1024]^T + bias; scatter into Q/K/V [B,H,S,D]
__global__ __launch_bounds__(256, 2) void k_gemm_qkv(
    const __bf16* __restrict__ A, const __bf16* __restrict__ Bt,
    const float* __restrict__ bias,
    __bf16* __restrict__ Qo, __bf16* __restrict__ Ko, __bf16* __restrict__ Vo) {
    __shared__ __bf16 As[128 * 40];
    __shared__ __bf16 Bs[128 * 40];
    const int Kd = 1024;
    int n0 = blockIdx.x * 128, m0 = blockIdx.y * 128;
    int tid = threadIdx.x;
    int wv = tid >> 6, lane = tid & 63;
    int wm = (wv >> 1) * 64, wn = (wv & 1) * 64;
    int quad = lane >> 4, l16 = lane & 15;
    f32x4 acc[4][4] = {};
    for (int k0 = 0; k0 < Kd; k0 += 32) {
        __syncthreads();
#pragma unroll
        for (int it = 0; it < 2; it++) {
            int c = tid + it * 256;
            int row = c >> 2, kc = (c & 3) << 3;
            *(uint4*)(&As[row * 40 + kc]) = *(const uint4*)(&A[(size_t)(m0 + row) * Kd + k0 + kc]);
            *(uint4*)(&Bs[row * 40 + kc]) = *(const uint4*)(&Bt[(size_t)(n0 + row) * Kd + k0 + kc]);
        }
        __syncthreads();
        bf16x8 af[4], bfr[4];
#pragma unroll
        for (int i = 0; i < 4; i++)
            af[i] = *(const bf16x8*)(&As[(wm + i * 16 + l16) * 40 + quad * 8]);
#pragma unroll
        for (int j = 0; j < 4; j++)
            bfr[j] = *(const bf16x8*)(&Bs[(wn + j * 16 + l16) * 40 + quad * 8]);
#pragma unroll
        for (int i = 0; i < 4; i++)
#pragma unroll
            for (int j = 0; j < 4; j++)
                acc[i][j] = MFMA16(af[i], bfr[j], acc[i][j]);
    }
#pragma unroll
    for (int i = 0; i < 4; i++) {
#pragma unroll
        for (int j = 0; j < 4; j++) {
            int n = n0 + wn + j * 16 + l16;
            float bv = bias[n];
            int sec = n >> 10, nl = n & 1023;
            int h = nl >> 6, d = nl & 63;
            __bf16* dst = sec == 0 ? Qo : (sec == 1 ? Ko : Vo);
            float scl = (sec == 0) ? 0.125f : 1.0f;  // fold 1/sqrt(64) into Q
#pragma unroll
            for (int r = 0; r < 4; r++) {
                int m = m0 + wm + i * 16 + quad * 4 + r;
                int bb = m >> 11, s = m & 2047;
                dst[((size_t)(bb * 16 + h) * 2048 + s) * 64 + d] =
                    (__bf16)((acc[i][j][r] + bv) * scl);
            }
        }
    }
}

// ---------------------------------------------------------------- proj GEMM
// out[4096,1024] = A[4096,1024] @ Bt[1024,1024]^T + bias  (fp32 out)
__global__ __launch_bounds__(256, 2) void k_gemm_proj(
    const __bf16* __restrict__ A, const __bf16* __restrict__ Bt,
    const float* __restrict__ bias, float* __restrict__ out) {
    __shared__ __bf16 As[128 * 40];
    __shared__ __bf16 Bs[128 * 40];
    const int Kd = 1024;
    int n0 = blockIdx.x * 128, m0 = blockIdx.y * 128;
    int tid = threadIdx.x;
    int wv = tid >> 6, lane = tid & 63;
    int wm = (wv >> 1) * 64, wn = (wv & 1) * 64;
    int quad = lane >> 4, l16 = lane & 15;
    f32x4 acc[4][4] = {};
    for (int k0 = 0; k0 < Kd; k0 += 32) {
        __syncthreads();
#pragma unroll
        for (int it = 0; it < 2; it++) {
            int c = tid + it * 256;
            int row = c >> 2, kc = (c & 3) << 3;
            *(uint4*)(&As[row * 40 + kc]) = *(const uint4*)(&A[(size_t)(m0 + row) * Kd + k0 + kc]);
            *(uint4*)(&Bs[row * 40 + kc]) = *(const uint4*)(&Bt[(size_t)(n0 + row) * Kd + k0 + kc]);
        }
        __syncthreads();
        bf16x8 af[4], bfr[4];
#pragma unroll
        for (int i = 0; i < 4; i++)
            af[i] = *(const bf16x8*)(&As[(wm + i * 16 + l16) * 40 + quad * 8]);
#pragma unroll
        for (int j = 0; j < 4; j++)
            bfr[j] = *(const bf16x8*)(&Bs[(wn + j * 16 + l16) * 40 + quad * 8]);
#pragma unroll
        for (int i = 0; i < 4; i++)
#pragma unroll
            for (int j = 0; j < 4; j++)
                acc[i][j] = MFMA16(af[i], bfr[j], acc[i][j]);
    }
#pragma unroll
    for (int i = 0; i < 4; i++) {
#pragma unroll
        for (int j = 0; j < 4; j++) {
            int n = n0 + wn + j * 16 + l16;
            float bv = bias[n];
#pragma unroll
            for (int r = 0; r < 4; r++) {
                int m = m0 + wm + i * 16 + quad * 4 + r;
                out[(size_t)m * 1024 + n] = acc[i][j][r] + bv;
            }
        }
    }
}

// ---------------------------------------------------------------- flash attention
// Q,K,V: [B,H,S,D] bf16 (Q pre-scaled).  Out: [B,S,E] bf16 (heads merged).
// Per block: one (b,h), 128-row Q tile; iterate 64-row K/V tiles, causal.
__global__ __launch_bounds__(256, 2) void k_attn(
    const __bf16* __restrict__ Qg, const __bf16* __restrict__ Kg,
    const __bf16* __restrict__ Vg, __bf16* __restrict__ Og) {
    __shared__ __bf16 Qs[128 * 72];
    __shared__ __bf16 Ps[128 * 72];  // union: Ks aliases rows 0..63
    __shared__ __bf16 Vt[64 * 72];   // V transposed: [d][kcol]
    __bf16* Ks = Ps;
    int bh = blockIdx.x >> 4;
    int qt = 15 - (blockIdx.x & 15);  // heavy (large-qt) blocks launch first
    int b = bh >> 4, h = bh & 15;
    const __bf16* Qp = Qg + (size_t)bh * 2048 * 64;
    const __bf16* Kp = Kg + (size_t)bh * 2048 * 64;
    const __bf16* Vp = Vg + (size_t)bh * 2048 * 64;
    int tid = threadIdx.x, wv = tid >> 6, lane = tid & 63;
    int quad = lane >> 4, l16 = lane & 15;

#pragma unroll
    for (int it = 0; it < 4; it++) {
        int c = tid + it * 256;
        int row = c >> 3, col = (c & 7) << 3;
        *(uint4*)(&Qs[row * 72 + col]) = *(const uint4*)(&Qp[(size_t)(qt * 128 + row) * 64 + col]);
    }
    float m_i[2][4], l_i[2][4];
    f32x4 acc_o[2][4] = {};
#pragma unroll
    for (int i = 0; i < 2; i++)
#pragma unroll
        for (int r = 0; r < 4; r++) { m_i[i][r] = -1e30f; l_i[i][r] = 0.f; }

    int ktmax = 2 * qt + 1;
    for (int kt = 0; kt <= ktmax; kt++) {
        __syncthreads();  // prior-iter Ps/Vt reads done before restaging
#pragma unroll
        for (int it = 0; it < 2; it++) {
            int c = tid + it * 256;
            int row = c >> 3, col = (c & 7) << 3;
            *(uint4*)(&Ks[row * 72 + col]) =
                *(const uint4*)(&Kp[(size_t)(kt * 64 + row) * 64 + col]);
            union { uint4 u; __bf16 e[8]; } vvu;
            vvu.u = *(const uint4*)(&Vp[(size_t)(kt * 64 + row) * 64 + col]);
#pragma unroll
            for (int u = 0; u < 8; u++) Vt[(col + u) * 72 + row] = vvu.e[u];
        }
        __syncthreads();
        // S = Q K^T : rows wv*32..+32, cols 0..63
        f32x4 sacc[2][4] = {};
#pragma unroll
        for (int ks = 0; ks < 2; ks++) {
            bf16x8 aq[2];
#pragma unroll
            for (int i = 0; i < 2; i++)
                aq[i] = *(const bf16x8*)(&Qs[(wv * 32 + i * 16 + l16) * 72 + ks * 32 + quad * 8]);
#pragma unroll
            for (int j = 0; j < 4; j++) {
                bf16x8 bk = *(const bf16x8*)(&Ks[(j * 16 + l16) * 72 + ks * 32 + quad * 8]);
#pragma unroll
                for (int i = 0; i < 2; i++) sacc[i][j] = MFMA16(aq[i], bk, sacc[i][j]);
            }
        }
        if (kt >= 2 * qt) {  // diagonal tiles: causal mask
#pragma unroll
            for (int i = 0; i < 2; i++)
#pragma unroll
                for (int j = 0; j < 4; j++)
#pragma unroll
                    for (int r = 0; r < 4; r++) {
                        int row = wv * 32 + i * 16 + quad * 4 + r;
                        int col = j * 16 + l16;
                        if (kt * 64 + col > qt * 128 + row) sacc[i][j][r] = -1e30f;
                    }
        }
        // online softmax (row = i*16+quad*4+r spread over 16 lanes of the quad)
        float alpha[2][4];
#pragma unroll
        for (int i = 0; i < 2; i++)
#pragma unroll
            for (int r = 0; r < 4; r++) {
                float mx = sacc[i][0][r];
#pragma unroll
                for (int j = 1; j < 4; j++) mx = fmaxf(mx, sacc[i][j][r]);
#pragma unroll
                for (int off = 1; off < 16; off <<= 1) mx = fmaxf(mx, __shfl_xor(mx, off));
                float mnew = fmaxf(m_i[i][r], mx);
                float al = __expf(m_i[i][r] - mnew);
                m_i[i][r] = mnew;
                alpha[i][r] = al;
                float rs = 0.f;
#pragma unroll
                for (int j = 0; j < 4; j++) {
                    float p0 = __expf(sacc[i][j][r] - mnew);
                    sacc[i][j][r] = p0;
                    rs += p0;
                }
#pragma unroll
                for (int off = 1; off < 16; off <<= 1) rs += __shfl_xor(rs, off);
                l_i[i][r] = l_i[i][r] * al + rs;
            }
        __syncthreads();  // all waves done reading Ks before P overwrites the union
#pragma unroll
        for (int i = 0; i < 2; i++)
#pragma unroll
            for (int j = 0; j < 4; j++)
#pragma unroll
                for (int r = 0; r < 4; r++)
                    Ps[(wv * 32 + i * 16 + quad * 4 + r) * 72 + j * 16 + l16] =
                        (__bf16)sacc[i][j][r];
#pragma unroll
        for (int i = 0; i < 2; i++)
#pragma unroll
            for (int jd = 0; jd < 4; jd++)
#pragma unroll
                for (int r = 0; r < 4; r++) acc_o[i][jd][r] *= alpha[i][r];
        __syncthreads();  // P visible
        // O += P @ V
#pragma unroll
        for (int ks = 0; ks < 2; ks++) {
            bf16x8 ap[2];
#pragma unroll
            for (int i = 0; i < 2; i++)
                ap[i] = *(const bf16x8*)(&Ps[(wv * 32 + i * 16 + l16) * 72 + ks * 32 + quad * 8]);
#pragma unroll
            for (int jd = 0; jd < 4; jd++) {
                bf16x8 bv = *(const bf16x8*)(&Vt[(jd * 16 + l16) * 72 + ks * 32 + quad * 8]);
#pragma unroll
                for (int i = 0; i < 2; i++) acc_o[i][jd] = MFMA16(ap[i], bv, acc_o[i][jd]);
            }
        }
    }
#pragma unroll
    for (int i = 0; i < 2; i++)
#pragma unroll
        for (int jd = 0; jd < 4; jd++)
#pragma unroll
            for (int r = 0; r < 4; r++) {
                int row = wv * 32 + i * 16 + quad * 4 + r;
                int s = qt * 128 + row;
                int d = jd * 16 + l16;
                float o = acc_o[i][jd][r] / l_i[i][r];
                Og[((size_t)b * 2048 + s) * 1024 + h * 64 + d] = (__bf16)o;
            }
}

// ---------------------------------------------------------------- launch
extern "C" void kernel_launch(void* const* d_in, const int* in_sizes, int n_in,
                              void* d_out, int out_size, void* d_ws, size_t ws_size,
                              hipStream_t stream) {
    const float* hs = (const float*)d_in[0];
    const float* w1 = (const float*)d_in[1];
    const float* b1 = (const float*)d_in[2];
    const float* w2 = (const float*)d_in[3];
    const float* b2 = (const float*)d_in[4];
    float* out = (float*)d_out;

    char* ws = (char*)d_ws;
    __bf16* hsb = (__bf16*)(ws);                               // 8 MB  [4096,1024]
    __bf16* w1t = (__bf16*)(ws + (size_t)8 * 1024 * 1024);     // 6 MB  [3072,1024]
    __bf16* w2t = (__bf16*)(ws + (size_t)14 * 1024 * 1024);    // 2 MB  [1024,1024]
    __bf16* Qb  = (__bf16*)(ws + (size_t)16 * 1024 * 1024);    // 8 MB  [B,H,S,D]
    __bf16* Kb  = (__bf16*)(ws + (size_t)24 * 1024 * 1024);    // 8 MB
    __bf16* Vb  = (__bf16*)(ws + (size_t)32 * 1024 * 1024);    // 8 MB
    __bf16* AOb = (__bf16*)(ws + (size_t)40 * 1024 * 1024);    // 8 MB  [B,S,E]

    k_cast_bf16<<<4096, 256, 0, stream>>>(hs, hsb, 4096 * 1024);
    k_transpose_cast<<<dim3(96, 32), dim3(32, 8), 0, stream>>>(w1, w1t, 1024, 3072);
    k_transpose_cast<<<dim3(32, 32), dim3(32, 8), 0, stream>>>(w2, w2t, 1024, 1024);
    k_gemm_qkv<<<dim3(24, 32), 256, 0, stream>>>(hsb, w1t, b1, Qb, Kb, Vb);
    k_attn<<<512, 256, 0, stream>>>(Qb, Kb, Vb, AOb);
    k_gemm_proj<<<dim3(8, 32), 256, 0, stream>>>(AOb, w2t, b2, out);
}

// Round 2
// 199.504 us; speedup vs baseline: 1.4284x; 1.4284x over previous
//
#include <hip/hip_runtime.h>
#include <stdint.h>

typedef __attribute__((ext_vector_type(8))) __bf16 bf16x8;
typedef __attribute__((ext_vector_type(4))) __bf16 bf16x4;
typedef __attribute__((ext_vector_type(4))) float f32x4;

#define MFMA16(a, b, c) __builtin_amdgcn_mfma_f32_16x16x32_bf16(a, b, c, 0, 0, 0)

// ---------------------------------------------------------------- casts
__global__ __launch_bounds__(256) void k_cast_bf16(const float* __restrict__ in,
                                                   __bf16* __restrict__ out, int n) {
    int i = (blockIdx.x * 256 + threadIdx.x) * 4;
    if (i >= n) return;
    float4 v = *(const float4*)(in + i);
    bf16x4 o;
    o.x = (__bf16)v.x; o.y = (__bf16)v.y; o.z = (__bf16)v.z; o.w = (__bf16)v.w;
    *(bf16x4*)(out + i) = o;
}

// in [R][C] fp32 -> out [C][R] bf16   (R, C multiples of 32)
__global__ __launch_bounds__(256) void k_transpose_cast(const float* __restrict__ in,
                                                        __bf16* __restrict__ out,
                                                        int R, int C) {
    __shared__ __bf16 tile[32][33];
    int c0 = blockIdx.x * 32, r0 = blockIdx.y * 32;
    int tx = threadIdx.x, ty = threadIdx.y;  // block (32, 8)
#pragma unroll
    for (int i = 0; i < 4; i++)
        tile[ty + i * 8][tx] = (__bf16)in[(size_t)(r0 + ty + i * 8) * C + c0 + tx];
    __syncthreads();
#pragma unroll
    for (int i = 0; i < 4; i++)
        out[(size_t)(c0 + ty + i * 8) * R + r0 + tx] = tile[tx][ty + i * 8];
}

// ---------------------------------------------------------------- QKV GEMM
// C[4096,3072] = A[4096,1024] @ Bt[3072,1024]^T + bias
// Q,K scattered into [B,H,S,D]; V scattered TRANSPOSED into [B,H,D,S].
__global__ __launch_bounds__(256, 2) void k_gemm_qkv(
    const __bf16* __restrict__ A, const __bf16* __restrict__ Bt,
    const float* __restrict__ bias,
    __bf16* __restrict__ Qo, __bf16* __restrict__ Ko, __bf16* __restrict__ Vo) {
    __shared__ __bf16 As[128 * 40];
    __shared__ __bf16 Bs[128 * 40];
    const int Kd = 1024;
    int n0 = blockIdx.x * 128, m0 = blockIdx.y * 128;
    int tid = threadIdx.x;
    int wv = tid >> 6, lane = tid & 63;
    int wm = (wv >> 1) * 64, wn = (wv & 1) * 64;
    int quad = lane >> 4, l16 = lane & 15;
    f32x4 acc[4][4] = {};
    for (int k0 = 0; k0 < Kd; k0 += 32) {
        __syncthreads();
#pragma unroll
        for (int it = 0; it < 2; it++) {
            int c = tid + it * 256;
            int row = c >> 2, kc = (c & 3) << 3;
            *(uint4*)(&As[row * 40 + kc]) = *(const uint4*)(&A[(size_t)(m0 + row) * Kd + k0 + kc]);
            *(uint4*)(&Bs[row * 40 + kc]) = *(const uint4*)(&Bt[(size_t)(n0 + row) * Kd + k0 + kc]);
        }
        __syncthreads();
        bf16x8 af[4], bfr[4];
#pragma unroll
        for (int i = 0; i < 4; i++)
            af[i] = *(const bf16x8*)(&As[(wm + i * 16 + l16) * 40 + quad * 8]);
#pragma unroll
        for (int j = 0; j < 4; j++)
            bfr[j] = *(const bf16x8*)(&Bs[(wn + j * 16 + l16) * 40 + quad * 8]);
#pragma unroll
        for (int i = 0; i < 4; i++)
#pragma unroll
            for (int j = 0; j < 4; j++)
                acc[i][j] = MFMA16(af[i], bfr[j], acc[i][j]);
    }
#pragma unroll
    for (int i = 0; i < 4; i++) {
#pragma unroll
        for (int j = 0; j < 4; j++) {
            int n = n0 + wn + j * 16 + l16;
            float bv = bias[n];
            int sec = n >> 10, nl = n & 1023;
            int h = nl >> 6, d = nl & 63;
            int mbase = m0 + wm + i * 16 + quad * 4;
            int bb = mbase >> 11, s = mbase & 2047;
            if (sec == 2) {  // V: transposed store [B,H,D,S], 4 contiguous s
                bf16x4 v4;
#pragma unroll
                for (int r = 0; r < 4; r++) v4[r] = (__bf16)(acc[i][j][r] + bv);
                *(bf16x4*)(&Vo[((size_t)(bb * 16 + h) * 64 + d) * 2048 + s]) = v4;
            } else {
                __bf16* dst = sec == 0 ? Qo : Ko;
                float scl = (sec == 0) ? 0.125f : 1.0f;  // fold 1/sqrt(64) into Q
#pragma unroll
                for (int r = 0; r < 4; r++)
                    dst[((size_t)(bb * 16 + h) * 2048 + (s + r)) * 64 + d] =
                        (__bf16)((acc[i][j][r] + bv) * scl);
            }
        }
    }
}

// ---------------------------------------------------------------- proj GEMM
// out[4096,1024] = A[4096,1024] @ Bt[1024,1024]^T + bias  (fp32 out)
__global__ __launch_bounds__(256, 2) void k_gemm_proj(
    const __bf16* __restrict__ A, const __bf16* __restrict__ Bt,
    const float* __restrict__ bias, float* __restrict__ out) {
    __shared__ __bf16 As[128 * 40];
    __shared__ __bf16 Bs[128 * 40];
    const int Kd = 1024;
    int n0 = blockIdx.x * 128, m0 = blockIdx.y * 128;
    int tid = threadIdx.x;
    int wv = tid >> 6, lane = tid & 63;
    int wm = (wv >> 1) * 64, wn = (wv & 1) * 64;
    int quad = lane >> 4, l16 = lane & 15;
    f32x4 acc[4][4] = {};
    for (int k0 = 0; k0 < Kd; k0 += 32) {
        __syncthreads();
#pragma unroll
        for (int it = 0; it < 2; it++) {
            int c = tid + it * 256;
            int row = c >> 2, kc = (c & 3) << 3;
            *(uint4*)(&As[row * 40 + kc]) = *(const uint4*)(&A[(size_t)(m0 + row) * Kd + k0 + kc]);
            *(uint4*)(&Bs[row * 40 + kc]) = *(const uint4*)(&Bt[(size_t)(n0 + row) * Kd + k0 + kc]);
        }
        __syncthreads();
        bf16x8 af[4], bfr[4];
#pragma unroll
        for (int i = 0; i < 4; i++)
            af[i] = *(const bf16x8*)(&As[(wm + i * 16 + l16) * 40 + quad * 8]);
#pragma unroll
        for (int j = 0; j < 4; j++)
            bfr[j] = *(const bf16x8*)(&Bs[(wn + j * 16 + l16) * 40 + quad * 8]);
#pragma unroll
        for (int i = 0; i < 4; i++)
#pragma unroll
            for (int j = 0; j < 4; j++)
                acc[i][j] = MFMA16(af[i], bfr[j], acc[i][j]);
    }
#pragma unroll
    for (int i = 0; i < 4; i++) {
#pragma unroll
        for (int j = 0; j < 4; j++) {
            int n = n0 + wn + j * 16 + l16;
            float bv = bias[n];
#pragma unroll
            for (int r = 0; r < 4; r++) {
                int m = m0 + wm + i * 16 + quad * 4 + r;
                out[(size_t)m * 1024 + n] = acc[i][j][r] + bv;
            }
        }
    }
}

// ---------------------------------------------------------------- flash attention (S^T form)
// Q,K: [B,H,S,D] bf16 (Q pre-scaled).  Vt: [B,H,D,S] bf16.  Out: [B,S,E] bf16.
// Block: one (b,h), TWO 64-row q-tiles (t, 31-t) -> uniform 33 tile-iterations.
// S^T = K @ Q^T via MFMA (K rows = A-frags, Q rows = B-frags); each thread owns
// one q-column per tile -> softmax reduce = in-register + 2 quad-shuffles.
// O^T = V^T @ P^T accumulated per thread; P round-trips LDS in natural [q][k].
__global__ __launch_bounds__(256, 2) void k_attn(
    const __bf16* __restrict__ Qg, const __bf16* __restrict__ Kg,
    const __bf16* __restrict__ Vtg, __bf16* __restrict__ Og) {
    __shared__ __bf16 Ks[64 * 72];
    __shared__ __bf16 Vt[64 * 72];
    __shared__ __bf16 Ps[64 * 72];
    int bh = blockIdx.x >> 4;
    int tp = blockIdx.x & 15;
    int b = bh >> 4, h = bh & 15;
    const __bf16* Qp = Qg + (size_t)bh * 2048 * 64;
    const __bf16* Kp = Kg + (size_t)bh * 2048 * 64;
    const __bf16* Vp = Vtg + (size_t)bh * 64 * 2048;
    int tid = threadIdx.x, wv = tid >> 6, lane = tid & 63;
    int quad = lane >> 4, l16 = lane & 15;
    int tt0 = tp, tt1 = 31 - tp;  // tile q-tile indices; tt1 > tt0 always

    // Loop-invariant Q B-fragments in registers (one q-column set per tile)
    bf16x8 qf[2][2];
#pragma unroll
    for (int ks = 0; ks < 2; ks++) {
        qf[0][ks] = *(const bf16x8*)(&Qp[(size_t)(tt0 * 64 + wv * 16 + l16) * 64 + ks * 32 + quad * 8]);
        qf[1][ks] = *(const bf16x8*)(&Qp[(size_t)(tt1 * 64 + wv * 16 + l16) * 64 + ks * 32 + quad * 8]);
    }
    float m_i[2] = {-1e30f, -1e30f}, l_i[2] = {0.f, 0.f};
    f32x4 acc_o[2][4] = {};

    int nkt = tt1 + 1;
    for (int kt = 0; kt < nkt; kt++) {
        __syncthreads();  // prior-iter Ks/Vt reads done before restaging
#pragma unroll
        for (int it = 0; it < 2; it++) {
            int idx = tid * 2 + it;
            int row = idx >> 3, cc = (idx & 7) * 8;
            *(uint4*)(&Ks[row * 72 + cc]) =
                *(const uint4*)(&Kp[(size_t)(kt * 64 + row) * 64 + cc]);
            *(uint4*)(&Vt[row * 72 + cc]) =
                *(const uint4*)(&Vp[(size_t)row * 2048 + kt * 64 + cc]);
        }
        __syncthreads();
        // shared A-fragments: K rows (for S^T) and V^T rows (for O^T)
        bf16x8 kf[4][2], vf[4][2];
#pragma unroll
        for (int i = 0; i < 4; i++)
#pragma unroll
            for (int ks = 0; ks < 2; ks++) {
                kf[i][ks] = *(const bf16x8*)(&Ks[(i * 16 + l16) * 72 + ks * 32 + quad * 8]);
                vf[i][ks] = *(const bf16x8*)(&Vt[(i * 16 + l16) * 72 + ks * 32 + quad * 8]);
            }
#pragma unroll
        for (int tt = 0; tt < 2; tt++) {
            int t = tt ? tt1 : tt0;
            if (kt > t) continue;  // wave-uniform
            // S^T tile: lane holds k-rows (i*16+quad*4+r), q-col (wv*16+l16)
            f32x4 s[4] = {};
#pragma unroll
            for (int ks = 0; ks < 2; ks++)
#pragma unroll
                for (int i = 0; i < 4; i++) s[i] = MFMA16(kf[i][ks], qf[tt][ks], s[i]);
            if (kt == t) {  // diagonal: causal mask
                int ql = wv * 16 + l16;
#pragma unroll
                for (int i = 0; i < 4; i++)
#pragma unroll
                    for (int r = 0; r < 4; r++)
                        if (i * 16 + quad * 4 + r > ql) s[i][r] = -1e30f;
            }
            // online softmax: one q-column per thread
            float mx = s[0][0];
#pragma unroll
            for (int i = 0; i < 4; i++)
#pragma unroll
                for (int r = 0; r < 4; r++) mx = fmaxf(mx, s[i][r]);
            mx = fmaxf(mx, __shfl_xor(mx, 16));
            mx = fmaxf(mx, __shfl_xor(mx, 32));
            float mnew = fmaxf(m_i[tt], mx);
            float al = __expf(m_i[tt] - mnew);
            m_i[tt] = mnew;
            float rs = 0.f;
#pragma unroll
            for (int i = 0; i < 4; i++) {
                bf16x4 pk;
#pragma unroll
                for (int r = 0; r < 4; r++) {
                    float p = __expf(s[i][r] - mnew);
                    rs += p;
                    pk[r] = (__bf16)p;
                }
                *(bf16x4*)(&Ps[(wv * 16 + l16) * 72 + i * 16 + quad * 4]) = pk;
            }
            rs += __shfl_xor(rs, 16);
            rs += __shfl_xor(rs, 32);
            l_i[tt] = l_i[tt] * al + rs;
#pragma unroll
            for (int i = 0; i < 4; i++)
#pragma unroll
                for (int r = 0; r < 4; r++) acc_o[tt][i][r] *= al;
            // O^T += V^T P^T  (P read back wave-locally; lgkmcnt orders it)
#pragma unroll
            for (int ks = 0; ks < 2; ks++) {
                bf16x8 pf = *(const bf16x8*)(&Ps[(wv * 16 + l16) * 72 + ks * 32 + quad * 8]);
#pragma unroll
                for (int i = 0; i < 4; i++) acc_o[tt][i] = MFMA16(vf[i][ks], pf, acc_o[tt][i]);
            }
        }
    }
    // epilogue: O^T[d][q] -> Og[b, s=q, h*64+d]
#pragma unroll
    for (int tt = 0; tt < 2; tt++) {
        int t = tt ? tt1 : tt0;
        int q = t * 64 + wv * 16 + l16;
        float inv = 1.f / l_i[tt];
#pragma unroll
        for (int i = 0; i < 4; i++) {
            bf16x4 o4;
#pragma unroll
            for (int r = 0; r < 4; r++) o4[r] = (__bf16)(acc_o[tt][i][r] * inv);
            *(bf16x4*)(&Og[((size_t)b * 2048 + q) * 1024 + h * 64 + i * 16 + quad * 4]) = o4;
        }
    }
}

// ---------------------------------------------------------------- launch
extern "C" void kernel_launch(void* const* d_in, const int* in_sizes, int n_in,
                              void* d_out, int out_size, void* d_ws, size_t ws_size,
                              hipStream_t stream) {
    const float* hs = (const float*)d_in[0];
    const float* w1 = (const float*)d_in[1];
    const float* b1 = (const float*)d_in[2];
    const float* w2 = (const float*)d_in[3];
    const float* b2 = (const float*)d_in[4];
    float* out = (float*)d_out;

    char* ws = (char*)d_ws;
    __bf16* hsb = (__bf16*)(ws);                               // 8 MB  [4096,1024]
    __bf16* w1t = (__bf16*)(ws + (size_t)8 * 1024 * 1024);     // 6 MB  [3072,1024]
    __bf16* w2t = (__bf16*)(ws + (size_t)14 * 1024 * 1024);    // 2 MB  [1024,1024]
    __bf16* Qb  = (__bf16*)(ws + (size_t)16 * 1024 * 1024);    // 8 MB  [B,H,S,D]
    __bf16* Kb  = (__bf16*)(ws + (size_t)24 * 1024 * 1024);    // 8 MB  [B,H,S,D]
    __bf16* Vb  = (__bf16*)(ws + (size_t)32 * 1024 * 1024);    // 8 MB  [B,H,D,S] (transposed)
    __bf16* AOb = (__bf16*)(ws + (size_t)40 * 1024 * 1024);    // 8 MB  [B,S,E]

    k_cast_bf16<<<4096, 256, 0, stream>>>(hs, hsb, 4096 * 1024);
    k_transpose_cast<<<dim3(96, 32), dim3(32, 8), 0, stream>>>(w1, w1t, 1024, 3072);
    k_transpose_cast<<<dim3(32, 32), dim3(32, 8), 0, stream>>>(w2, w2t, 1024, 1024);
    k_gemm_qkv<<<dim3(24, 32), 256, 0, stream>>>(hsb, w1t, b1, Qb, Kb, Vb);
    k_attn<<<512, 256, 0, stream>>>(Qb, Kb, Vb, AOb);
    k_gemm_proj<<<dim3(8, 32), 256, 0, stream>>>(AOb, w2t, b2, out);
}

// Round 3
// 188.952 us; speedup vs baseline: 1.5082x; 1.0558x over previous
//
#include <hip/hip_runtime.h>
#include <stdint.h>

typedef __attribute__((ext_vector_type(8))) __bf16 bf16x8;
typedef __attribute__((ext_vector_type(4))) __bf16 bf16x4;
typedef __attribute__((ext_vector_type(4))) float f32x4;

#define MFMA16(a, b, c) __builtin_amdgcn_mfma_f32_16x16x32_bf16(a, b, c, 0, 0, 0)

// async 16B global->LDS: lds dest must be wave-uniform base; lane writes at base+lane*16
__device__ __forceinline__ void async_ld16(const __bf16* g, __bf16* lds_base) {
    __builtin_amdgcn_global_load_lds(
        (const __attribute__((address_space(1))) void*)g,
        (__attribute__((address_space(3))) void*)lds_base, 16, 0, 0);
}

// ---------------------------------------------------------------- casts
__global__ __launch_bounds__(256) void k_cast_bf16(const float* __restrict__ in,
                                                   __bf16* __restrict__ out, int n) {
    int i = (blockIdx.x * 256 + threadIdx.x) * 4;
    if (i >= n) return;
    float4 v = *(const float4*)(in + i);
    bf16x4 o;
    o.x = (__bf16)v.x; o.y = (__bf16)v.y; o.z = (__bf16)v.z; o.w = (__bf16)v.w;
    *(bf16x4*)(out + i) = o;
}

// in [R][C] fp32 -> out [C][R] bf16   (R, C multiples of 32)
__global__ __launch_bounds__(256) void k_transpose_cast(const float* __restrict__ in,
                                                        __bf16* __restrict__ out,
                                                        int R, int C) {
    __shared__ __bf16 tile[32][33];
    int c0 = blockIdx.x * 32, r0 = blockIdx.y * 32;
    int tx = threadIdx.x, ty = threadIdx.y;  // block (32, 8)
#pragma unroll
    for (int i = 0; i < 4; i++)
        tile[ty + i * 8][tx] = (__bf16)in[(size_t)(r0 + ty + i * 8) * C + c0 + tx];
    __syncthreads();
#pragma unroll
    for (int i = 0; i < 4; i++)
        out[(size_t)(c0 + ty + i * 8) * R + r0 + tx] = tile[tx][ty + i * 8];
}

// ---------------------------------------------------------------- QKV GEMM (m97-style)
// C[4096,3072] = A[4096,1024] @ Bt[3072,1024]^T + bias
// Q,K scattered into [B,H,S,D]; V scattered TRANSPOSED into [B,H,D,S].
__global__ __launch_bounds__(256, 2) void k_gemm_qkv(
    const __bf16* __restrict__ A, const __bf16* __restrict__ Bt,
    const float* __restrict__ bias,
    __bf16* __restrict__ Qo, __bf16* __restrict__ Ko, __bf16* __restrict__ Vo) {
    __shared__ __bf16 As[128 * 32];  // unpadded: required by global_load_lds lane mapping
    __shared__ __bf16 Bs[128 * 32];
    const int Kd = 1024;
    int n0 = blockIdx.x * 128, m0 = blockIdx.y * 128;
    int tid = threadIdx.x;
    int wv = tid >> 6, lane = tid & 63;
    int wm = (wv >> 1) * 64, wn = (wv & 1) * 64;
    int quad = lane >> 4, l16 = lane & 15;
    int lrow = lane >> 2, lcol = (lane & 3) * 8;  // staging: lane -> (row, col)
    f32x4 acc[4][4] = {};
    for (int k0 = 0; k0 < Kd; k0 += 32) {
        __syncthreads();
#pragma unroll
        for (int r = 0; r < 2; r++) {
            int row = r * 64 + wv * 16;  // wave-uniform
            async_ld16(&A[(size_t)(m0 + row + lrow) * Kd + k0 + lcol], &As[row * 32]);
            async_ld16(&Bt[(size_t)(n0 + row + lrow) * Kd + k0 + lcol], &Bs[row * 32]);
        }
        __syncthreads();
        bf16x8 af[4], bfr[4];
#pragma unroll
        for (int i = 0; i < 4; i++)
            af[i] = *(const bf16x8*)(&As[(wm + i * 16 + l16) * 32 + quad * 8]);
#pragma unroll
        for (int j = 0; j < 4; j++)
            bfr[j] = *(const bf16x8*)(&Bs[(wn + j * 16 + l16) * 32 + quad * 8]);
#pragma unroll
        for (int i = 0; i < 4; i++)
#pragma unroll
            for (int j = 0; j < 4; j++)
                acc[i][j] = MFMA16(af[i], bfr[j], acc[i][j]);
    }
#pragma unroll
    for (int i = 0; i < 4; i++) {
#pragma unroll
        for (int j = 0; j < 4; j++) {
            int n = n0 + wn + j * 16 + l16;
            float bv = bias[n];
            int sec = n >> 10, nl = n & 1023;
            int h = nl >> 6, d = nl & 63;
            int mbase = m0 + wm + i * 16 + quad * 4;
            int bb = mbase >> 11, s = mbase & 2047;
            if (sec == 2) {  // V: transposed store [B,H,D,S], 4 contiguous s
                bf16x4 v4;
#pragma unroll
                for (int r = 0; r < 4; r++) v4[r] = (__bf16)(acc[i][j][r] + bv);
                *(bf16x4*)(&Vo[((size_t)(bb * 16 + h) * 64 + d) * 2048 + s]) = v4;
            } else {
                __bf16* dst = sec == 0 ? Qo : Ko;
                float scl = (sec == 0) ? 0.125f : 1.0f;  // fold 1/sqrt(64) into Q
#pragma unroll
                for (int r = 0; r < 4; r++)
                    dst[((size_t)(bb * 16 + h) * 2048 + (s + r)) * 64 + d] =
                        (__bf16)((acc[i][j][r] + bv) * scl);
            }
        }
    }
}

// ---------------------------------------------------------------- proj GEMM (m97-style)
// out[4096,1024] = A[4096,1024] @ Bt[1024,1024]^T + bias  (fp32 out)
__global__ __launch_bounds__(256, 2) void k_gemm_proj(
    const __bf16* __restrict__ A, const __bf16* __restrict__ Bt,
    const float* __restrict__ bias, float* __restrict__ out) {
    __shared__ __bf16 As[128 * 32];
    __shared__ __bf16 Bs[128 * 32];
    const int Kd = 1024;
    int n0 = blockIdx.x * 128, m0 = blockIdx.y * 128;
    int tid = threadIdx.x;
    int wv = tid >> 6, lane = tid & 63;
    int wm = (wv >> 1) * 64, wn = (wv & 1) * 64;
    int quad = lane >> 4, l16 = lane & 15;
    int lrow = lane >> 2, lcol = (lane & 3) * 8;
    f32x4 acc[4][4] = {};
    for (int k0 = 0; k0 < Kd; k0 += 32) {
        __syncthreads();
#pragma unroll
        for (int r = 0; r < 2; r++) {
            int row = r * 64 + wv * 16;
            async_ld16(&A[(size_t)(m0 + row + lrow) * Kd + k0 + lcol], &As[row * 32]);
            async_ld16(&Bt[(size_t)(n0 + row + lrow) * Kd + k0 + lcol], &Bs[row * 32]);
        }
        __syncthreads();
        bf16x8 af[4], bfr[4];
#pragma unroll
        for (int i = 0; i < 4; i++)
            af[i] = *(const bf16x8*)(&As[(wm + i * 16 + l16) * 32 + quad * 8]);
#pragma unroll
        for (int j = 0; j < 4; j++)
            bfr[j] = *(const bf16x8*)(&Bs[(wn + j * 16 + l16) * 32 + quad * 8]);
#pragma unroll
        for (int i = 0; i < 4; i++)
#pragma unroll
            for (int j = 0; j < 4; j++)
                acc[i][j] = MFMA16(af[i], bfr[j], acc[i][j]);
    }
#pragma unroll
    for (int i = 0; i < 4; i++) {
#pragma unroll
        for (int j = 0; j < 4; j++) {
            int n = n0 + wn + j * 16 + l16;
            float bv = bias[n];
#pragma unroll
            for (int r = 0; r < 4; r++) {
                int m = m0 + wm + i * 16 + quad * 4 + r;
                out[(size_t)m * 1024 + n] = acc[i][j][r] + bv;
            }
        }
    }
}

// ---------------------------------------------------------------- flash attention (S^T form)
// Q,K: [B,H,S,D] bf16 (Q pre-scaled).  Vt: [B,H,D,S] bf16.  Out: [B,S,E] bf16.
// Block: ONE (b,h) 64-row q-tile -> grid 1024 (4 blocks/CU resident).
// Heavy tiles (large t) launch first for tail balance.
__global__ __launch_bounds__(256, 2) void k_attn(
    const __bf16* __restrict__ Qg, const __bf16* __restrict__ Kg,
    const __bf16* __restrict__ Vtg, __bf16* __restrict__ Og) {
    __shared__ __bf16 Ks[64 * 72];
    __shared__ __bf16 Vt[64 * 72];
    __shared__ __bf16 Ps[64 * 72];
    int bh = blockIdx.x & 31;
    int t = 31 - (blockIdx.x >> 5);  // q-tile index, heavy first
    int b = bh >> 4, h = bh & 15;
    const __bf16* Qp = Qg + (size_t)bh * 2048 * 64;
    const __bf16* Kp = Kg + (size_t)bh * 2048 * 64;
    const __bf16* Vp = Vtg + (size_t)bh * 64 * 2048;
    int tid = threadIdx.x, wv = tid >> 6, lane = tid & 63;
    int quad = lane >> 4, l16 = lane & 15;

    // Loop-invariant Q B-fragments (this thread's q-column = t*64 + wv*16 + l16)
    bf16x8 qf[2];
#pragma unroll
    for (int ks = 0; ks < 2; ks++)
        qf[ks] = *(const bf16x8*)(&Qp[(size_t)(t * 64 + wv * 16 + l16) * 64 + ks * 32 + quad * 8]);
    float m_i = -1e30f, l_i = 0.f;
    f32x4 acc_o[4] = {};

    for (int kt = 0; kt <= t; kt++) {
        __syncthreads();  // prior-iter Ks/Vt reads done before restaging
#pragma unroll
        for (int it = 0; it < 2; it++) {
            int idx = tid * 2 + it;
            int row = idx >> 3, cc = (idx & 7) * 8;
            *(uint4*)(&Ks[row * 72 + cc]) =
                *(const uint4*)(&Kp[(size_t)(kt * 64 + row) * 64 + cc]);
            *(uint4*)(&Vt[row * 72 + cc]) =
                *(const uint4*)(&Vp[(size_t)row * 2048 + kt * 64 + cc]);
        }
        __syncthreads();
        // A-fragments: K rows (for S^T) and V^T rows (for O^T)
        bf16x8 kf[4][2], vf[4][2];
#pragma unroll
        for (int i = 0; i < 4; i++)
#pragma unroll
            for (int ks = 0; ks < 2; ks++) {
                kf[i][ks] = *(const bf16x8*)(&Ks[(i * 16 + l16) * 72 + ks * 32 + quad * 8]);
                vf[i][ks] = *(const bf16x8*)(&Vt[(i * 16 + l16) * 72 + ks * 32 + quad * 8]);
            }
        // S^T tile: lane holds k-rows (i*16+quad*4+r), q-col (wv*16+l16)
        f32x4 s[4] = {};
#pragma unroll
        for (int ks = 0; ks < 2; ks++)
#pragma unroll
            for (int i = 0; i < 4; i++) s[i] = MFMA16(kf[i][ks], qf[ks], s[i]);
        if (kt == t) {  // diagonal: causal mask
            int ql = wv * 16 + l16;
#pragma unroll
            for (int i = 0; i < 4; i++)
#pragma unroll
                for (int r = 0; r < 4; r++)
                    if (i * 16 + quad * 4 + r > ql) s[i][r] = -1e30f;
        }
        // online softmax: one q-column per thread
        float mx = s[0][0];
#pragma unroll
        for (int i = 0; i < 4; i++)
#pragma unroll
            for (int r = 0; r < 4; r++) mx = fmaxf(mx, s[i][r]);
        mx = fmaxf(mx, __shfl_xor(mx, 16));
        mx = fmaxf(mx, __shfl_xor(mx, 32));
        float mnew = fmaxf(m_i, mx);
        float al = __expf(m_i - mnew);
        m_i = mnew;
        float rs = 0.f;
#pragma unroll
        for (int i = 0; i < 4; i++) {
            bf16x4 pk;
#pragma unroll
            for (int r = 0; r < 4; r++) {
                float p = __expf(s[i][r] - mnew);
                rs += p;
                pk[r] = (__bf16)p;
            }
            *(bf16x4*)(&Ps[(wv * 16 + l16) * 72 + i * 16 + quad * 4]) = pk;
        }
        rs += __shfl_xor(rs, 16);
        rs += __shfl_xor(rs, 32);
        l_i = l_i * al + rs;
#pragma unroll
        for (int i = 0; i < 4; i++)
#pragma unroll
            for (int r = 0; r < 4; r++) acc_o[i][r] *= al;
        // O^T += V^T P^T  (P read back wave-locally; lgkmcnt orders it)
#pragma unroll
        for (int ks = 0; ks < 2; ks++) {
            bf16x8 pf = *(const bf16x8*)(&Ps[(wv * 16 + l16) * 72 + ks * 32 + quad * 8]);
#pragma unroll
            for (int i = 0; i < 4; i++) acc_o[i] = MFMA16(vf[i][ks], pf, acc_o[i]);
        }
    }
    // epilogue: O^T[d][q] -> Og[b, s=q, h*64+d]
    int q = t * 64 + wv * 16 + l16;
    float inv = 1.f / l_i;
#pragma unroll
    for (int i = 0; i < 4; i++) {
        bf16x4 o4;
#pragma unroll
        for (int r = 0; r < 4; r++) o4[r] = (__bf16)(acc_o[i][r] * inv);
        *(bf16x4*)(&Og[((size_t)b * 2048 + q) * 1024 + h * 64 + i * 16 + quad * 4]) = o4;
    }
}

// ---------------------------------------------------------------- launch
extern "C" void kernel_launch(void* const* d_in, const int* in_sizes, int n_in,
                              void* d_out, int out_size, void* d_ws, size_t ws_size,
                              hipStream_t stream) {
    const float* hs = (const float*)d_in[0];
    const float* w1 = (const float*)d_in[1];
    const float* b1 = (const float*)d_in[2];
    const float* w2 = (const float*)d_in[3];
    const float* b2 = (const float*)d_in[4];
    float* out = (float*)d_out;

    char* ws = (char*)d_ws;
    __bf16* hsb = (__bf16*)(ws);                               // 8 MB  [4096,1024]
    __bf16* w1t = (__bf16*)(ws + (size_t)8 * 1024 * 1024);     // 6 MB  [3072,1024]
    __bf16* w2t = (__bf16*)(ws + (size_t)14 * 1024 * 1024);    // 2 MB  [1024,1024]
    __bf16* Qb  = (__bf16*)(ws + (size_t)16 * 1024 * 1024);    // 8 MB  [B,H,S,D]
    __bf16* Kb  = (__bf16*)(ws + (size_t)24 * 1024 * 1024);    // 8 MB  [B,H,S,D]
    __bf16* Vb  = (__bf16*)(ws + (size_t)32 * 1024 * 1024);    // 8 MB  [B,H,D,S] (transposed)
    __bf16* AOb = (__bf16*)(ws + (size_t)40 * 1024 * 1024);    // 8 MB  [B,S,E]

    k_cast_bf16<<<4096, 256, 0, stream>>>(hs, hsb, 4096 * 1024);
    k_transpose_cast<<<dim3(96, 32), dim3(32, 8), 0, stream>>>(w1, w1t, 1024, 3072);
    k_transpose_cast<<<dim3(32, 32), dim3(32, 8), 0, stream>>>(w2, w2t, 1024, 1024);
    k_gemm_qkv<<<dim3(24, 32), 256, 0, stream>>>(hsb, w1t, b1, Qb, Kb, Vb);
    k_attn<<<1024, 256, 0, stream>>>(Qb, Kb, Vb, AOb);
    k_gemm_proj<<<dim3(8, 32), 256, 0, stream>>>(AOb, w2t, b2, out);
}